// Round 10
// baseline (667.247 us; speedup 1.0000x reference)
//
#include <hip/hip_runtime.h>
#include <hip/hip_bf16.h>

// GraphProp via linearity trick:
//   a[n] = Wl@(deg[n]*h[n]) + Wr@S[n] + deg[n]*b,  S[n] = sum_{e:dst=n} h[src]
// R10: R9's GEMM restructure (A-frags straight from global; W-only 20KB LDS;
// 32x128 wave tiles) with the launch-merge REVERTED: R9's merged a+gh launch
// raced gh's output (PA) against a's output (same PA alias). Sequential order
// a -> gi -> gh restores the R8-proven aliasing contract.
// Graph path: bucket CSR + in-LDS sort + per-node 8-wide gather (R8-proven).

#define NN 50000
#define NE 1600000
#define HH 128
#define TT 2
#define NB 1563   // ceil(NN/32) buckets
#define GG 64     // scatter groups
#define EPB 25000 // edges per group = NE/GG
#define MAXB 3072 // max edges/bucket in LDS (mean 1024 -> +64 sigma safe)

typedef _Float16 half8 __attribute__((ext_vector_type(8)));
typedef _Float16 half2v __attribute__((ext_vector_type(2)));
typedef float floatx4 __attribute__((ext_vector_type(4)));

__device__ __forceinline__ float bf2f(unsigned short u) {
    union { unsigned int i; float f; } c;
    c.i = ((unsigned int)u) << 16;
    return c.f;
}

// ---------- dtype detectors: flags[0]=src int64, flags[1]=floats are fp32 ----------
__global__ void detect_kernel(const unsigned short* __restrict__ hv_u16,
                              const int* __restrict__ src, int* __restrict__ flags) {
    int i = threadIdx.x;  // 64 threads
    int garbage = 0;
    for (int k = 0; k < 4; k++) {
        unsigned short u = hv_u16[2 * (i * 4 + k)];
        int e = (u >> 7) & 0xFF;
        if (e >= 0x90 || (e <= 0x60 && (u & 0x7FFF) != 0)) garbage++;
    }
    unsigned long long gb = __ballot(garbage > 0);
    int odd = src[2 * i + 1];
    unsigned long long bal = __ballot(odd == 0);
    if (i == 0) {
        flags[1] = (__popcll(gb) >= 8) ? 1 : 0;
        flags[0] = (bal == 0xFFFFFFFFFFFFFFFFull) ? 1 : 0;
    }
}

// ---------- hv hi/lo split ----------
__global__ void split_kernel(const void* __restrict__ in, _Float16* __restrict__ ph,
                             _Float16* __restrict__ pl, int n, const int* __restrict__ flags) {
    int i = blockIdx.x * blockDim.x + threadIdx.x;
    if (i >= n) return;
    float v = flags[1] ? ((const float*)in)[i] : bf2f(((const unsigned short*)in)[i]);
    _Float16 h = (_Float16)v;
    ph[i] = h;
    pl[i] = (_Float16)(v - (float)h);
}

// ---------- fused 3-tensor weight split ----------
__global__ void split3_kernel(
    const void* __restrict__ i1, _Float16* __restrict__ h1, _Float16* __restrict__ l1, int n1,
    const void* __restrict__ i2, _Float16* __restrict__ h2, _Float16* __restrict__ l2, int n2,
    const void* __restrict__ i3, _Float16* __restrict__ h3, _Float16* __restrict__ l3, int n3,
    const int* __restrict__ flags) {
    int i = blockIdx.x * blockDim.x + threadIdx.x;
    const void* in; _Float16 *ph, *pl; int j = i;
    if (j < n1) { in = i1; ph = h1; pl = l1; }
    else { j -= n1;
        if (j < n2) { in = i2; ph = h2; pl = l2; }
        else { j -= n2; if (j >= n3) return; in = i3; ph = h3; pl = l3; }
    }
    float v = flags[1] ? ((const float*)in)[j] : bf2f(((const unsigned short*)in)[j]);
    _Float16 h = (_Float16)v;
    ph[j] = h;
    pl[j] = (_Float16)(v - (float)h);
}

// ---------- fused 3-tensor bias convert ----------
__global__ void conv3_kernel(
    const void* __restrict__ i1, float* __restrict__ o1, int n1,
    const void* __restrict__ i2, float* __restrict__ o2, int n2,
    const void* __restrict__ i3, float* __restrict__ o3, int n3,
    const int* __restrict__ flags) {
    int i = blockIdx.x * blockDim.x + threadIdx.x;
    const void* in; float* out; int j = i;
    if (j < n1) { in = i1; out = o1; }
    else { j -= n1;
        if (j < n2) { in = i2; out = o2; }
        else { j -= n2; if (j >= n3) return; in = i3; out = o3; }
    }
    out[j] = flags[1] ? ((const float*)in)[j] : bf2f(((const unsigned short*)in)[j]);
}

// ---------- Phase A: per-group bucket histograms ----------
__global__ __launch_bounds__(256) void bucket_hist_kernel(const int* __restrict__ dst,
                                                          int* __restrict__ counts /*[NB][GG]*/) {
    __shared__ int h[NB];
    int g = blockIdx.x, tid = threadIdx.x;
    for (int b = tid; b < NB; b += 256) h[b] = 0;
    __syncthreads();
    int beg = g * EPB, end = min(NE, beg + EPB);
    for (int e = beg + tid; e < end; e += 256) atomicAdd(&h[dst[e] >> 5], 1);
    __syncthreads();
    for (int b = tid; b < NB; b += 256) counts[b * GG + g] = h[b];
}

// ---------- bucket totals ----------
__global__ __launch_bounds__(256) void bucket_sum_kernel(const int* __restrict__ counts,
                                                         int* __restrict__ bsum) {
    int b = blockIdx.x * 4 + (threadIdx.x >> 6);
    int lane = threadIdx.x & 63;
    if (b >= NB) return;
    int v = counts[b * GG + lane];
    #pragma unroll
    for (int off = 32; off > 0; off >>= 1) v += __shfl_down(v, off, 64);
    if (lane == 0) bsum[b] = v;
}

// ---------- exclusive scan of bsum -> bbase[0..NB] ----------
__global__ void bucket_scan_kernel(const int* __restrict__ bsum, int* __restrict__ bbase) {
    __shared__ int wsum[16];
    __shared__ int s_running;
    int tid = threadIdx.x, lane = tid & 63, w = tid >> 6;
    if (tid == 0) s_running = 0;
    __syncthreads();
    int nch = (NB + 1024) / 1024;  // 2
    for (int c = 0; c < nch; c++) {
        int idx = c * 1024 + tid;
        int v = (idx < NB) ? bsum[idx] : 0;
        int s = v;
        #pragma unroll
        for (int off = 1; off < 64; off <<= 1) {
            int t = __shfl_up(s, off, 64);
            if (lane >= off) s += t;
        }
        if (lane == 63) wsum[w] = s;
        __syncthreads();
        if (w == 0) {
            int ws = (lane < 16) ? wsum[lane] : 0;
            #pragma unroll
            for (int off = 1; off < 16; off <<= 1) {
                int t = __shfl_up(ws, off, 64);
                if (lane >= off) ws += t;
            }
            if (lane < 16) wsum[lane] = ws;
        }
        __syncthreads();
        int incl = s + ((w > 0) ? wsum[w - 1] : 0);
        int base = s_running;
        if (idx <= NB) bbase[idx] = base + incl - v;
        __syncthreads();
        if (tid == 1023) s_running = base + incl;
        __syncthreads();
    }
}

// ---------- per-(bucket,group) segment offsets ----------
__global__ __launch_bounds__(256) void bucket_offsets_kernel(const int* __restrict__ counts,
                                                             const int* __restrict__ bbase,
                                                             int* __restrict__ offsets) {
    int b = blockIdx.x * 4 + (threadIdx.x >> 6);
    int lane = threadIdx.x & 63;
    if (b >= NB) return;
    int v = counts[b * GG + lane];
    int s = v;
    #pragma unroll
    for (int off = 1; off < 64; off <<= 1) {
        int t = __shfl_up(s, off, 64);
        if (lane >= off) s += t;
    }
    offsets[b * GG + lane] = bbase[b] + s - v;
}

// ---------- Phase B: scatter packed edges (bucket-major) ----------
__global__ __launch_bounds__(256) void bucket_scatter_kernel(
    const int* __restrict__ src, const int* __restrict__ dst,
    const int* __restrict__ offsets, int* __restrict__ pairs,
    const int* __restrict__ flags) {
    __shared__ int ofs[NB];
    int g = blockIdx.x, tid = threadIdx.x;
    for (int b = tid; b < NB; b += 256) ofs[b] = offsets[b * GG + g];
    __syncthreads();
    int beg = g * EPB, end = min(NE, beg + EPB);
    int f64 = flags[0];
    for (int e = beg + tid; e < end; e += 256) {
        int d = dst[e];
        int s = f64 ? src[2 * e] : src[e];
        int pos = atomicAdd(&ofs[d >> 5], 1);
        pairs[pos] = ((d & 31) << 16) | s;   // NN < 2^16
    }
}

// ---------- Phase C: in-bucket counting sort -> per-node CSR, row/deg ----------
__global__ __launch_bounds__(256) void bucket_sort_kernel(
    const int* __restrict__ bbase, int* __restrict__ pairs,
    int* __restrict__ row, int* __restrict__ deg) {
    __shared__ int buf[MAXB];
    __shared__ int cnt[32];
    __shared__ int off[32];
    int b = blockIdx.x, tid = threadIdx.x;
    int beg = bbase[b], end = bbase[b + 1];
    int nE = end - beg;
    if (nE > MAXB) nE = MAXB;
    if (tid < 32) cnt[tid] = 0;
    __syncthreads();
    for (int i = tid; i < nE; i += 256) {
        int pk = pairs[beg + i];
        buf[i] = pk;
        atomicAdd(&cnt[pk >> 16], 1);
    }
    __syncthreads();
    if (tid < 64) {
        int lane = tid;
        int v = (lane < 32) ? cnt[lane] : 0;
        int s = v;
        #pragma unroll
        for (int o = 1; o < 32; o <<= 1) {
            int t = __shfl_up(s, o, 64);
            if (lane >= o) s += t;
        }
        if (lane < 32) {
            off[lane] = s - v;
            int gn = b * 32 + lane;
            if (gn < NN) { row[gn] = beg + s - v; deg[gn] = v; }
        }
        if (lane == 0 && b == NB - 1) row[NN] = end;
    }
    __syncthreads();
    if (tid < 32) cnt[tid] = off[tid];
    __syncthreads();
    for (int i = tid; i < nE; i += 256) {
        int pk = buf[i];
        int pos = atomicAdd(&cnt[pk >> 16], 1);
        pairs[beg + pos] = pk & 0xFFFF;
    }
}

// ---------- per-node gather, 8-wide MLP (R8-proven) ----------
__global__ __launch_bounds__(64) void gather_kernel(
    const int* __restrict__ row, const int* __restrict__ csr,
    const _Float16* __restrict__ hvH,
    _Float16* __restrict__ SH, _Float16* __restrict__ SL) {
    int n = blockIdx.x;
    int lane = threadIdx.x;
    const half2v* hv2 = (const half2v*)hvH;
    int beg = row[n], end = row[n + 1];
    float sx = 0.f, sy = 0.f;
    int e = beg;
    for (; e + 8 <= end; e += 8) {
        int s0 = csr[e], s1 = csr[e + 1], s2 = csr[e + 2], s3 = csr[e + 3];
        int s4 = csr[e + 4], s5 = csr[e + 5], s6 = csr[e + 6], s7 = csr[e + 7];
        half2v v0 = hv2[(size_t)s0 * 64 + lane];
        half2v v1 = hv2[(size_t)s1 * 64 + lane];
        half2v v2 = hv2[(size_t)s2 * 64 + lane];
        half2v v3 = hv2[(size_t)s3 * 64 + lane];
        half2v v4 = hv2[(size_t)s4 * 64 + lane];
        half2v v5 = hv2[(size_t)s5 * 64 + lane];
        half2v v6 = hv2[(size_t)s6 * 64 + lane];
        half2v v7 = hv2[(size_t)s7 * 64 + lane];
        sx += (float)v0.x + (float)v1.x + (float)v2.x + (float)v3.x
            + (float)v4.x + (float)v5.x + (float)v6.x + (float)v7.x;
        sy += (float)v0.y + (float)v1.y + (float)v2.y + (float)v3.y
            + (float)v4.y + (float)v5.y + (float)v6.y + (float)v7.y;
    }
    for (; e < end; e++) {
        half2v v = hv2[(size_t)csr[e] * 64 + lane];
        sx += (float)v.x; sy += (float)v.y;
    }
    half2v hx, lx;
    hx.x = (_Float16)sx; lx.x = (_Float16)(sx - (float)hx.x);
    hx.y = (_Float16)sy; lx.y = (_Float16)(sy - (float)hx.y);
    ((half2v*)SH)[(size_t)n * 64 + lane] = hx;
    ((half2v*)SL)[(size_t)n * 64 + lane] = lx;
}

// ---------- split-precision MFMA GEMM, A from global, W-only LDS ----------
// C[m,n] = epi( sum_k Avirt[m,k] * W[n,k] );  acc += Ah*Wh + Al*Wh + Ah*Wl.
// Block: 128 m-rows x 128 n-cols (n0 = blockIdx.y*128); 4 waves, wave-tile 32x128.
struct GemmOp {
    const _Float16 *AhA, *AlA, *AhB, *AlB;  // virtual concat cols [0,Kleft) | [Kleft,K)
    int Kleft, K;
    const _Float16 *Wh, *Wl;                // [Nout x K] row-major, pre-split
    const float* bias;
    _Float16 *outH, *outL;
    int ldc, mode;   // mode 0: deg-scaled left + hi/lo out; mode 1: f16 out
};

__global__ __launch_bounds__(256) void mfma_gemm_kernel(
    GemmOp op, const int* __restrict__ deg, int M) {
    __shared__ _Float16 Wsh[128][40];  // +8 pad (20 KB total LDS)
    __shared__ _Float16 Wsl[128][40];
    int n0 = blockIdx.y * 128;
    int tid = threadIdx.x;
    int m0 = blockIdx.x * 128;
    int wave = tid >> 6, lane = tid & 63;
    int lr = lane & 15, quad = lane >> 4;
    int wm = wave * 32;
    floatx4 acc[2][8] = {};
    int r0 = tid >> 2, c0 = (tid & 3) * 8;   // W staging: rows r0, r0+64; chunk c0

    float dsc[2] = {1.f, 1.f};               // per-lane deg of the A-frag row
    if (op.mode == 0) {
        #pragma unroll
        for (int mt = 0; mt < 2; mt++) {
            int gm = m0 + wm + mt * 16 + lr;
            dsc[mt] = (gm < M) ? (float)deg[gm] : 0.f;
        }
    }

    for (int k0 = 0; k0 < op.K; k0 += 32) {
        // W tile -> registers (global)
        half8 wh0 = *(const half8*)(op.Wh + (size_t)(n0 + r0) * op.K + k0 + c0);
        half8 wh1 = *(const half8*)(op.Wh + (size_t)(n0 + r0 + 64) * op.K + k0 + c0);
        half8 wl0 = *(const half8*)(op.Wl + (size_t)(n0 + r0) * op.K + k0 + c0);
        half8 wl1 = *(const half8*)(op.Wl + (size_t)(n0 + r0 + 64) * op.K + k0 + c0);
        // A fragments straight from global: 16 rows x 64B contiguous per frag
        bool left = (k0 < op.Kleft);
        const _Float16* Ph = left ? op.AhA : op.AhB;
        const _Float16* Pl = left ? op.AlA : op.AlB;
        int astr = left ? op.Kleft : (op.K - op.Kleft);
        int kk = (left ? k0 : k0 - op.Kleft) + quad * 8;
        half8 afh[2] = {}, afl[2] = {};
        #pragma unroll
        for (int mt = 0; mt < 2; mt++) {
            int gm = m0 + wm + mt * 16 + lr;
            if (gm < M) {
                afh[mt] = *(const half8*)(Ph + (size_t)gm * astr + kk);
                afl[mt] = *(const half8*)(Pl + (size_t)gm * astr + kk);
            }
        }
        if (op.mode == 0 && left) {  // reconstruct, scale by deg[row], re-split
            #pragma unroll
            for (int mt = 0; mt < 2; mt++)
                #pragma unroll
                for (int q = 0; q < 8; q++) {
                    float f = ((float)afh[mt][q] + (float)afl[mt][q]) * dsc[mt];
                    _Float16 h = (_Float16)f;
                    afh[mt][q] = h; afl[mt][q] = (_Float16)(f - (float)h);
                }
        }
        __syncthreads();  // previous iteration's W reads done
        *(half8*)&Wsh[r0][c0] = wh0;   *(half8*)&Wsh[r0 + 64][c0] = wh1;
        *(half8*)&Wsl[r0][c0] = wl0;   *(half8*)&Wsl[r0 + 64][c0] = wl1;
        __syncthreads();
        #pragma unroll
        for (int nt = 0; nt < 8; nt++) {
            half8 bh = *(const half8*)&Wsh[nt * 16 + lr][quad * 8];
            half8 bl = *(const half8*)&Wsl[nt * 16 + lr][quad * 8];
            #pragma unroll
            for (int mt = 0; mt < 2; mt++) {
                acc[mt][nt] = __builtin_amdgcn_mfma_f32_16x16x32_f16(afh[mt], bh, acc[mt][nt], 0, 0, 0);
                acc[mt][nt] = __builtin_amdgcn_mfma_f32_16x16x32_f16(afl[mt], bh, acc[mt][nt], 0, 0, 0);
                acc[mt][nt] = __builtin_amdgcn_mfma_f32_16x16x32_f16(afh[mt], bl, acc[mt][nt], 0, 0, 0);
            }
        }
    }

    // D layout: col = lane&15, row = quad*4 + reg  [verified R4-R8]
    #pragma unroll
    for (int mt = 0; mt < 2; mt++) {
        #pragma unroll
        for (int r = 0; r < 4; r++) {
            int m = m0 + wm + mt * 16 + quad * 4 + r;
            if (m >= M) continue;
            #pragma unroll
            for (int nt = 0; nt < 8; nt++) {
                int n = n0 + nt * 16 + lr;
                float v = acc[mt][nt][r];
                size_t o = (size_t)m * op.ldc + n;
                if (op.mode == 0) {
                    v += (float)deg[m] * op.bias[n];
                    _Float16 h = (_Float16)v;
                    op.outH[o] = h; op.outL[o] = (_Float16)(v - (float)h);
                } else {
                    op.outH[o] = (_Float16)(v + op.bias[n]);
                }
            }
        }
    }
}

// ---------- fused GRU gates (R6-proven) ----------
__global__ void gate_kernel(const _Float16* __restrict__ gi,
                            const _Float16* __restrict__ gh,
                            _Float16* __restrict__ hvH, _Float16* __restrict__ hvL,
                            void* __restrict__ outv,
                            const int* __restrict__ flags, int writeOut, int total) {
    int idx = blockIdx.x * blockDim.x + threadIdx.x;
    if (idx >= total) return;
    int n = idx >> 7;
    int j = idx & 127;
    size_t base = (size_t)n * 384;
    float i_r = (float)gi[base + j];
    float i_z = (float)gi[base + 128 + j];
    float i_n = (float)gi[base + 256 + j];
    float h_r = (float)gh[base + j];
    float h_z = (float)gh[base + 128 + j];
    float h_n = (float)gh[base + 256 + j];
    float h = (float)hvH[idx] + (float)hvL[idx];
    float r = 1.f / (1.f + __expf(-(i_r + h_r)));
    float z = 1.f / (1.f + __expf(-(i_z + h_z)));
    float nn = tanhf(i_n + r * h_n);
    float hn = (1.f - z) * nn + z * h;
    _Float16 hh = (_Float16)hn;
    hvH[idx] = hh;
    hvL[idx] = (_Float16)(hn - (float)hh);
    if (writeOut) {
        if (flags[1]) ((float*)outv)[idx] = hn;
        else ((__hip_bfloat16*)outv)[idx] = __float2bfloat16(hn);
    }
}

extern "C" void kernel_launch(void* const* d_in, const int* in_sizes, int n_in,
                              void* d_out, int out_size, void* d_ws, size_t ws_size,
                              hipStream_t stream) {
    const void* hv_in   = d_in[0];
    const int* edge_src = (const int*)d_in[1];
    const int* edge_dst = (const int*)d_in[2];
    const void* msg_W = d_in[3];
    const void* msg_b = d_in[4];
    const void* gWih  = d_in[5];
    const void* gWhh  = d_in[6];
    const void* gbih  = d_in[7];
    const void* gbhh  = d_in[8];

    // ---- workspace carve-up (~125 MB, R8-proven level) ----
    char* p = (char*)d_ws;
    auto alloc = [&](size_t bytes) -> void* {
        void* r = (void*)p;
        p += (bytes + 255) & ~(size_t)255;
        return r;
    };
    int* flags   = (int*)alloc(256);
    int* deg     = (int*)alloc((size_t)NN * 4);
    int* row     = (int*)alloc((size_t)(NN + 1) * 4);
    int* counts  = (int*)alloc((size_t)NB * GG * 4);
    int* bsum    = (int*)alloc((size_t)NB * 4);
    int* bbase   = (int*)alloc((size_t)(NB + 1) * 4);
    int* offsets = (int*)alloc((size_t)NB * GG * 4);
    int* pairs   = (int*)alloc((size_t)NE * 4);        // becomes sorted csr
    _Float16* wMsgH = (_Float16*)alloc((size_t)TT * 256 * 256 * 2);
    _Float16* wMsgL = (_Float16*)alloc((size_t)TT * 256 * 256 * 2);
    _Float16* wIhH  = (_Float16*)alloc((size_t)TT * 384 * 256 * 2);
    _Float16* wIhL  = (_Float16*)alloc((size_t)TT * 384 * 256 * 2);
    _Float16* wHhH  = (_Float16*)alloc((size_t)TT * 384 * 128 * 2);
    _Float16* wHhL  = (_Float16*)alloc((size_t)TT * 384 * 128 * 2);
    float* bMsg  = (float*)alloc((size_t)TT * 256 * 4);
    float* bIh   = (float*)alloc((size_t)TT * 384 * 4);
    float* bHh   = (float*)alloc((size_t)TT * 384 * 4);
    _Float16* hvH = (_Float16*)alloc((size_t)NN * HH * 2);
    _Float16* hvL = (_Float16*)alloc((size_t)NN * HH * 2);
    char* PA = (char*)alloc((size_t)NN * 256 * 2 * 2);   // aH+aL -> gh
    char* PB = (char*)alloc((size_t)NN * 384 * 2);       // SH+SL -> gi
    (void)ws_size; (void)in_sizes; (void)n_in; (void)out_size;

    _Float16* aH = (_Float16*)PA;
    _Float16* aL = (_Float16*)(PA + (size_t)NN * 256 * 2);
    _Float16* gh = (_Float16*)PA;
    _Float16* SH = (_Float16*)PB;
    _Float16* SL = (_Float16*)(PB + (size_t)NN * HH * 2);
    _Float16* gi = (_Float16*)PB;

    // ---- dtype detection + conversions (fused) ----
    detect_kernel<<<1, 64, 0, stream>>>((const unsigned short*)hv_in, edge_src, flags);
    split_kernel<<<(NN * HH + 255) / 256, 256, 0, stream>>>(hv_in, hvH, hvL, NN * HH, flags);
    {
        int n1 = TT * 256 * 256, n2 = TT * 384 * 256, n3 = TT * 384 * 128;
        split3_kernel<<<(n1 + n2 + n3 + 255) / 256, 256, 0, stream>>>(
            msg_W, wMsgH, wMsgL, n1, gWih, wIhH, wIhL, n2, gWhh, wHhH, wHhL, n3, flags);
    }
    {
        int n1 = TT * 256, n2 = TT * 384, n3 = TT * 384;
        conv3_kernel<<<(n1 + n2 + n3 + 255) / 256, 256, 0, stream>>>(
            msg_b, bMsg, n1, gbih, bIh, n2, gbhh, bHh, n3, flags);
    }

    // ---- bucket-CSR build + in-bucket sort -> per-node CSR ----
    bucket_hist_kernel<<<GG, 256, 0, stream>>>(edge_dst, counts);
    bucket_sum_kernel<<<(NB + 3) / 4, 256, 0, stream>>>(counts, bsum);
    bucket_scan_kernel<<<1, 1024, 0, stream>>>(bsum, bbase);
    bucket_offsets_kernel<<<(NB + 3) / 4, 256, 0, stream>>>(counts, bbase, offsets);
    bucket_scatter_kernel<<<GG, 256, 0, stream>>>(edge_src, edge_dst, offsets, pairs, flags);
    bucket_sort_kernel<<<NB, 256, 0, stream>>>(bbase, pairs, row, deg);

    int mt128 = (NN + 127) / 128;  // 391

    for (int t = 0; t < TT; t++) {
        // S planes from per-node 8-wide gather
        gather_kernel<<<NN, 64, 0, stream>>>(row, pairs, hvH, SH, SL);

        // a = [deg*hv | S] @ msg_W^T + deg*b  -> aH/aL (PA)
        GemmOp opa = { hvH, hvL, SH, SL, 128, 256,
                       wMsgH + (size_t)t * 256 * 256, wMsgL + (size_t)t * 256 * 256,
                       bMsg + (size_t)t * 256, aH, aL, 256, 0 };
        mfma_gemm_kernel<<<dim3(mt128, 2), 256, 0, stream>>>(opa, deg, NN);

        // gi = f16(a @ Wih^T + bih) -> PB (S dead)
        GemmOp opi = { aH, aL, aH, aL, 256, 256,
                       wIhH + (size_t)t * 384 * 256, wIhL + (size_t)t * 384 * 256,
                       bIh + (size_t)t * 384, gi, nullptr, 384, 1 };
        mfma_gemm_kernel<<<dim3(mt128, 3), 256, 0, stream>>>(opi, deg, NN);

        // gh = f16(hv @ Whh^T + bhh) -> PA (a dead NOW — sequential, unlike R9)
        GemmOp opg = { hvH, hvL, hvH, hvL, 128, 128,
                       wHhH + (size_t)t * 384 * 128, wHhL + (size_t)t * 384 * 128,
                       bHh + (size_t)t * 384, gh, nullptr, 384, 1 };
        mfma_gemm_kernel<<<dim3(mt128, 3), 256, 0, stream>>>(opg, deg, NN);

        // GRU gates; hi/lo state planes in place; dtype-aware output on last round
        gate_kernel<<<(NN * HH + 255) / 256, 256, 0, stream>>>(
            gi, gh, hvH, hvL, d_out, flags, (t == TT - 1) ? 1 : 0, NN * HH);
    }
}

// Round 11
// 600.247 us; speedup vs baseline: 1.1116x; 1.1116x over previous
//
#include <hip/hip_runtime.h>
#include <hip/hip_bf16.h>

// GraphProp via linearity trick, now fused one level deeper:
//   gi = Wih@a + bih = (Wih@Wmsg)@A1 + deg*(Wih@msg_b) + bih = Wc@A1 + deg*c1 + bih
//   where A1 = [deg*hv | S],  S[n] = sum_{e:dst=n} hv[src].
// R11: `a` is never materialized (R10 showed the GEMM chain is bound by a's
// 51MB x (write + ~1.8x read) HBM traffic). Wc/c1 precomputed on device once.
// Grid swizzle: n-tile = blockIdx.x (fast) -> A m-tile reuse across n-blocks.
// Aliasing order: gather->S(PB); gi(PA) reads S+hv; gh(PB over dead S); gate.
// Graph path (bucket CSR + in-LDS sort + 8-wide per-node gather): R8-proven.

#define NN 50000
#define NE 1600000
#define HH 128
#define TT 2
#define NB 1563   // ceil(NN/32) buckets
#define GG 64     // scatter groups
#define EPB 25000 // edges per group = NE/GG
#define MAXB 3072 // max edges/bucket in LDS (mean 1024 -> +64 sigma safe)

typedef _Float16 half8 __attribute__((ext_vector_type(8)));
typedef _Float16 half2v __attribute__((ext_vector_type(2)));
typedef float floatx4 __attribute__((ext_vector_type(4)));

__device__ __forceinline__ float bf2f(unsigned short u) {
    union { unsigned int i; float f; } c;
    c.i = ((unsigned int)u) << 16;
    return c.f;
}
__device__ __forceinline__ float ldf(const void* p, size_t i, int f32) {
    return f32 ? ((const float*)p)[i] : bf2f(((const unsigned short*)p)[i]);
}

// ---------- dtype detectors: flags[0]=src int64, flags[1]=floats are fp32 ----------
__global__ void detect_kernel(const unsigned short* __restrict__ hv_u16,
                              const int* __restrict__ src, int* __restrict__ flags) {
    int i = threadIdx.x;  // 64 threads
    int garbage = 0;
    for (int k = 0; k < 4; k++) {
        unsigned short u = hv_u16[2 * (i * 4 + k)];
        int e = (u >> 7) & 0xFF;
        if (e >= 0x90 || (e <= 0x60 && (u & 0x7FFF) != 0)) garbage++;
    }
    unsigned long long gb = __ballot(garbage > 0);
    int odd = src[2 * i + 1];
    unsigned long long bal = __ballot(odd == 0);
    if (i == 0) {
        flags[1] = (__popcll(gb) >= 8) ? 1 : 0;
        flags[0] = (bal == 0xFFFFFFFFFFFFFFFFull) ? 1 : 0;
    }
}

// ---------- hi/lo split of a flag-dtype tensor ----------
__global__ void split_kernel(const void* __restrict__ in, _Float16* __restrict__ ph,
                             _Float16* __restrict__ pl, int n, const int* __restrict__ flags) {
    int i = blockIdx.x * blockDim.x + threadIdx.x;
    if (i >= n) return;
    float v = ldf(in, i, flags[1]);
    _Float16 h = (_Float16)v;
    ph[i] = h;
    pl[i] = (_Float16)(v - (float)h);
}

// ---------- fused 3-tensor bias convert ----------
__global__ void conv3_kernel(
    const void* __restrict__ i1, float* __restrict__ o1, int n1,
    const void* __restrict__ i2, float* __restrict__ o2, int n2,
    const void* __restrict__ i3, float* __restrict__ o3, int n3,
    const int* __restrict__ flags) {
    int i = blockIdx.x * blockDim.x + threadIdx.x;
    const void* in; float* out; int j = i;
    if (j < n1) { in = i1; out = o1; }
    else { j -= n1;
        if (j < n2) { in = i2; out = o2; }
        else { j -= n2; if (j >= n3) return; in = i3; out = o3; }
    }
    out[j] = ldf(in, j, flags[1]);
}

// ---------- Wc = Wih @ Wmsg (fp32), emitted directly as hi/lo f16 planes ----------
// block = t*384 + r (768 blocks); thread k in [0,256): Wc[t,r,k] = sum_c Wih[t,r,c]*Wmsg[t,c,k]
__global__ __launch_bounds__(256) void wc_kernel(
    const void* __restrict__ gWih, const void* __restrict__ msgW,
    _Float16* __restrict__ wcH, _Float16* __restrict__ wcL,
    const int* __restrict__ flags) {
    __shared__ float wrow[256];
    int tr = blockIdx.x;
    int t = tr / 384;
    int k = threadIdx.x;
    int f32 = flags[1];
    wrow[k] = ldf(gWih, (size_t)tr * 256 + k, f32);
    __syncthreads();
    float s = 0.f;
    size_t base = (size_t)t * 256 * 256;
    for (int c = 0; c < 256; c++)
        s += wrow[c] * ldf(msgW, base + (size_t)c * 256 + k, f32);
    _Float16 h = (_Float16)s;
    wcH[(size_t)tr * 256 + k] = h;
    wcL[(size_t)tr * 256 + k] = (_Float16)(s - (float)h);
}

// ---------- c1 = Wih @ msg_b (fp32, per t) ----------
__global__ void c1_kernel(const void* __restrict__ gWih, const float* __restrict__ bMsg,
                          float* __restrict__ c1, const int* __restrict__ flags) {
    int tr = blockIdx.x * 64 + threadIdx.x;  // TT*384 total
    if (tr >= TT * 384) return;
    int t = tr / 384;
    int f32 = flags[1];
    float s = 0.f;
    for (int c = 0; c < 256; c++)
        s += ldf(gWih, (size_t)tr * 256 + c, f32) * bMsg[t * 256 + c];
    c1[tr] = s;
}

// ---------- Phase A: per-group bucket histograms ----------
__global__ __launch_bounds__(256) void bucket_hist_kernel(const int* __restrict__ dst,
                                                          int* __restrict__ counts /*[NB][GG]*/) {
    __shared__ int h[NB];
    int g = blockIdx.x, tid = threadIdx.x;
    for (int b = tid; b < NB; b += 256) h[b] = 0;
    __syncthreads();
    int beg = g * EPB, end = min(NE, beg + EPB);
    for (int e = beg + tid; e < end; e += 256) atomicAdd(&h[dst[e] >> 5], 1);
    __syncthreads();
    for (int b = tid; b < NB; b += 256) counts[b * GG + g] = h[b];
}

// ---------- bucket totals ----------
__global__ __launch_bounds__(256) void bucket_sum_kernel(const int* __restrict__ counts,
                                                         int* __restrict__ bsum) {
    int b = blockIdx.x * 4 + (threadIdx.x >> 6);
    int lane = threadIdx.x & 63;
    if (b >= NB) return;
    int v = counts[b * GG + lane];
    #pragma unroll
    for (int off = 32; off > 0; off >>= 1) v += __shfl_down(v, off, 64);
    if (lane == 0) bsum[b] = v;
}

// ---------- exclusive scan of bsum -> bbase[0..NB] ----------
__global__ void bucket_scan_kernel(const int* __restrict__ bsum, int* __restrict__ bbase) {
    __shared__ int wsum[16];
    __shared__ int s_running;
    int tid = threadIdx.x, lane = tid & 63, w = tid >> 6;
    if (tid == 0) s_running = 0;
    __syncthreads();
    int nch = (NB + 1024) / 1024;  // 2
    for (int c = 0; c < nch; c++) {
        int idx = c * 1024 + tid;
        int v = (idx < NB) ? bsum[idx] : 0;
        int s = v;
        #pragma unroll
        for (int off = 1; off < 64; off <<= 1) {
            int t = __shfl_up(s, off, 64);
            if (lane >= off) s += t;
        }
        if (lane == 63) wsum[w] = s;
        __syncthreads();
        if (w == 0) {
            int ws = (lane < 16) ? wsum[lane] : 0;
            #pragma unroll
            for (int off = 1; off < 16; off <<= 1) {
                int t = __shfl_up(ws, off, 64);
                if (lane >= off) ws += t;
            }
            if (lane < 16) wsum[lane] = ws;
        }
        __syncthreads();
        int incl = s + ((w > 0) ? wsum[w - 1] : 0);
        int base = s_running;
        if (idx <= NB) bbase[idx] = base + incl - v;
        __syncthreads();
        if (tid == 1023) s_running = base + incl;
        __syncthreads();
    }
}

// ---------- per-(bucket,group) segment offsets ----------
__global__ __launch_bounds__(256) void bucket_offsets_kernel(const int* __restrict__ counts,
                                                             const int* __restrict__ bbase,
                                                             int* __restrict__ offsets) {
    int b = blockIdx.x * 4 + (threadIdx.x >> 6);
    int lane = threadIdx.x & 63;
    if (b >= NB) return;
    int v = counts[b * GG + lane];
    int s = v;
    #pragma unroll
    for (int off = 1; off < 64; off <<= 1) {
        int t = __shfl_up(s, off, 64);
        if (lane >= off) s += t;
    }
    offsets[b * GG + lane] = bbase[b] + s - v;
}

// ---------- Phase B: scatter packed edges (bucket-major) ----------
__global__ __launch_bounds__(256) void bucket_scatter_kernel(
    const int* __restrict__ src, const int* __restrict__ dst,
    const int* __restrict__ offsets, int* __restrict__ pairs,
    const int* __restrict__ flags) {
    __shared__ int ofs[NB];
    int g = blockIdx.x, tid = threadIdx.x;
    for (int b = tid; b < NB; b += 256) ofs[b] = offsets[b * GG + g];
    __syncthreads();
    int beg = g * EPB, end = min(NE, beg + EPB);
    int f64 = flags[0];
    for (int e = beg + tid; e < end; e += 256) {
        int d = dst[e];
        int s = f64 ? src[2 * e] : src[e];
        int pos = atomicAdd(&ofs[d >> 5], 1);
        pairs[pos] = ((d & 31) << 16) | s;   // NN < 2^16
    }
}

// ---------- Phase C: in-bucket counting sort -> per-node CSR, row/deg ----------
__global__ __launch_bounds__(256) void bucket_sort_kernel(
    const int* __restrict__ bbase, int* __restrict__ pairs,
    int* __restrict__ row, int* __restrict__ deg) {
    __shared__ int buf[MAXB];
    __shared__ int cnt[32];
    __shared__ int off[32];
    int b = blockIdx.x, tid = threadIdx.x;
    int beg = bbase[b], end = bbase[b + 1];
    int nE = end - beg;
    if (nE > MAXB) nE = MAXB;
    if (tid < 32) cnt[tid] = 0;
    __syncthreads();
    for (int i = tid; i < nE; i += 256) {
        int pk = pairs[beg + i];
        buf[i] = pk;
        atomicAdd(&cnt[pk >> 16], 1);
    }
    __syncthreads();
    if (tid < 64) {
        int lane = tid;
        int v = (lane < 32) ? cnt[lane] : 0;
        int s = v;
        #pragma unroll
        for (int o = 1; o < 32; o <<= 1) {
            int t = __shfl_up(s, o, 64);
            if (lane >= o) s += t;
        }
        if (lane < 32) {
            off[lane] = s - v;
            int gn = b * 32 + lane;
            if (gn < NN) { row[gn] = beg + s - v; deg[gn] = v; }
        }
        if (lane == 0 && b == NB - 1) row[NN] = end;
    }
    __syncthreads();
    if (tid < 32) cnt[tid] = off[tid];
    __syncthreads();
    for (int i = tid; i < nE; i += 256) {
        int pk = buf[i];
        int pos = atomicAdd(&cnt[pk >> 16], 1);
        pairs[beg + pos] = pk & 0xFFFF;
    }
}

// ---------- per-node gather, 8-wide MLP (R8-proven) ----------
__global__ __launch_bounds__(64) void gather_kernel(
    const int* __restrict__ row, const int* __restrict__ csr,
    const _Float16* __restrict__ hvH,
    _Float16* __restrict__ SH, _Float16* __restrict__ SL) {
    int n = blockIdx.x;
    int lane = threadIdx.x;
    const half2v* hv2 = (const half2v*)hvH;
    int beg = row[n], end = row[n + 1];
    float sx = 0.f, sy = 0.f;
    int e = beg;
    for (; e + 8 <= end; e += 8) {
        int s0 = csr[e], s1 = csr[e + 1], s2 = csr[e + 2], s3 = csr[e + 3];
        int s4 = csr[e + 4], s5 = csr[e + 5], s6 = csr[e + 6], s7 = csr[e + 7];
        half2v v0 = hv2[(size_t)s0 * 64 + lane];
        half2v v1 = hv2[(size_t)s1 * 64 + lane];
        half2v v2 = hv2[(size_t)s2 * 64 + lane];
        half2v v3 = hv2[(size_t)s3 * 64 + lane];
        half2v v4 = hv2[(size_t)s4 * 64 + lane];
        half2v v5 = hv2[(size_t)s5 * 64 + lane];
        half2v v6 = hv2[(size_t)s6 * 64 + lane];
        half2v v7 = hv2[(size_t)s7 * 64 + lane];
        sx += (float)v0.x + (float)v1.x + (float)v2.x + (float)v3.x
            + (float)v4.x + (float)v5.x + (float)v6.x + (float)v7.x;
        sy += (float)v0.y + (float)v1.y + (float)v2.y + (float)v3.y
            + (float)v4.y + (float)v5.y + (float)v6.y + (float)v7.y;
    }
    for (; e < end; e++) {
        half2v v = hv2[(size_t)csr[e] * 64 + lane];
        sx += (float)v.x; sy += (float)v.y;
    }
    half2v hx, lx;
    hx.x = (_Float16)sx; lx.x = (_Float16)(sx - (float)hx.x);
    hx.y = (_Float16)sy; lx.y = (_Float16)(sy - (float)hx.y);
    ((half2v*)SH)[(size_t)n * 64 + lane] = hx;
    ((half2v*)SL)[(size_t)n * 64 + lane] = lx;
}

// ---------- split-precision MFMA GEMM, A from global, W-only LDS ----------
// C[m,n] = f16( sum_k Avirt[m,k]*W[n,k] + bias[n] + (mode0: deg[m]*bias2[n]) )
// acc += Ah*Wh + Al*Wh + Ah*Wl. mode 0 also deg-scales the left A half.
// Grid: blockIdx.x = n-tile (FAST -> A-tile L2/L3 reuse), blockIdx.y = m-tile.
struct GemmOp {
    const _Float16 *AhA, *AlA, *AhB, *AlB;  // virtual concat cols [0,Kleft) | [Kleft,K)
    int Kleft, K;
    const _Float16 *Wh, *Wl;                // [Nout x K] row-major, pre-split
    const float* bias;                      // bih / bhh
    const float* bias2;                     // c1 (mode 0) or null
    _Float16* outH;
    int ldc, mode;
};

__global__ __launch_bounds__(256) void mfma_gemm_kernel(
    GemmOp op, const int* __restrict__ deg, int M) {
    __shared__ _Float16 Wsh[128][40];  // +8 pad (20 KB total LDS)
    __shared__ _Float16 Wsl[128][40];
    int n0 = blockIdx.x * 128;
    int m0 = blockIdx.y * 128;
    int tid = threadIdx.x;
    int wave = tid >> 6, lane = tid & 63;
    int lr = lane & 15, quad = lane >> 4;
    int wm = wave * 32;
    floatx4 acc[2][8] = {};
    int r0 = tid >> 2, c0 = (tid & 3) * 8;   // W staging: rows r0, r0+64; chunk c0

    float dsc[2] = {1.f, 1.f};
    if (op.mode == 0) {
        #pragma unroll
        for (int mt = 0; mt < 2; mt++) {
            int gm = m0 + wm + mt * 16 + lr;
            dsc[mt] = (gm < M) ? (float)deg[gm] : 0.f;
        }
    }

    for (int k0 = 0; k0 < op.K; k0 += 32) {
        half8 wh0 = *(const half8*)(op.Wh + (size_t)(n0 + r0) * op.K + k0 + c0);
        half8 wh1 = *(const half8*)(op.Wh + (size_t)(n0 + r0 + 64) * op.K + k0 + c0);
        half8 wl0 = *(const half8*)(op.Wl + (size_t)(n0 + r0) * op.K + k0 + c0);
        half8 wl1 = *(const half8*)(op.Wl + (size_t)(n0 + r0 + 64) * op.K + k0 + c0);
        bool left = (k0 < op.Kleft);
        const _Float16* Ph = left ? op.AhA : op.AhB;
        const _Float16* Pl = left ? op.AlA : op.AlB;
        int astr = left ? op.Kleft : (op.K - op.Kleft);
        int kk = (left ? k0 : k0 - op.Kleft) + quad * 8;
        half8 afh[2] = {}, afl[2] = {};
        #pragma unroll
        for (int mt = 0; mt < 2; mt++) {
            int gm = m0 + wm + mt * 16 + lr;
            if (gm < M) {
                afh[mt] = *(const half8*)(Ph + (size_t)gm * astr + kk);
                afl[mt] = *(const half8*)(Pl + (size_t)gm * astr + kk);
            }
        }
        if (op.mode == 0 && left) {  // reconstruct, deg-scale, re-split
            #pragma unroll
            for (int mt = 0; mt < 2; mt++)
                #pragma unroll
                for (int q = 0; q < 8; q++) {
                    float f = ((float)afh[mt][q] + (float)afl[mt][q]) * dsc[mt];
                    _Float16 h = (_Float16)f;
                    afh[mt][q] = h; afl[mt][q] = (_Float16)(f - (float)h);
                }
        }
        __syncthreads();
        *(half8*)&Wsh[r0][c0] = wh0;   *(half8*)&Wsh[r0 + 64][c0] = wh1;
        *(half8*)&Wsl[r0][c0] = wl0;   *(half8*)&Wsl[r0 + 64][c0] = wl1;
        __syncthreads();
        #pragma unroll
        for (int nt = 0; nt < 8; nt++) {
            half8 bh = *(const half8*)&Wsh[nt * 16 + lr][quad * 8];
            half8 bl = *(const half8*)&Wsl[nt * 16 + lr][quad * 8];
            #pragma unroll
            for (int mt = 0; mt < 2; mt++) {
                acc[mt][nt] = __builtin_amdgcn_mfma_f32_16x16x32_f16(afh[mt], bh, acc[mt][nt], 0, 0, 0);
                acc[mt][nt] = __builtin_amdgcn_mfma_f32_16x16x32_f16(afl[mt], bh, acc[mt][nt], 0, 0, 0);
                acc[mt][nt] = __builtin_amdgcn_mfma_f32_16x16x32_f16(afh[mt], bl, acc[mt][nt], 0, 0, 0);
            }
        }
    }

    // D layout: col = lane&15, row = quad*4 + reg  [verified R4-R10]
    #pragma unroll
    for (int mt = 0; mt < 2; mt++) {
        #pragma unroll
        for (int r = 0; r < 4; r++) {
            int m = m0 + wm + mt * 16 + quad * 4 + r;
            if (m >= M) continue;
            float d2 = (op.mode == 0) ? (float)deg[m] : 0.f;
            #pragma unroll
            for (int nt = 0; nt < 8; nt++) {
                int n = n0 + nt * 16 + lr;
                float v = acc[mt][nt][r] + op.bias[n];
                if (op.mode == 0) v += d2 * op.bias2[n];
                op.outH[(size_t)m * op.ldc + n] = (_Float16)v;
            }
        }
    }
}

// ---------- fused GRU gates (R6-proven) ----------
__global__ void gate_kernel(const _Float16* __restrict__ gi,
                            const _Float16* __restrict__ gh,
                            _Float16* __restrict__ hvH, _Float16* __restrict__ hvL,
                            void* __restrict__ outv,
                            const int* __restrict__ flags, int writeOut, int total) {
    int idx = blockIdx.x * blockDim.x + threadIdx.x;
    if (idx >= total) return;
    int n = idx >> 7;
    int j = idx & 127;
    size_t base = (size_t)n * 384;
    float i_r = (float)gi[base + j];
    float i_z = (float)gi[base + 128 + j];
    float i_n = (float)gi[base + 256 + j];
    float h_r = (float)gh[base + j];
    float h_z = (float)gh[base + 128 + j];
    float h_n = (float)gh[base + 256 + j];
    float h = (float)hvH[idx] + (float)hvL[idx];
    float r = 1.f / (1.f + __expf(-(i_r + h_r)));
    float z = 1.f / (1.f + __expf(-(i_z + h_z)));
    float nn = tanhf(i_n + r * h_n);
    float hn = (1.f - z) * nn + z * h;
    _Float16 hh = (_Float16)hn;
    hvH[idx] = hh;
    hvL[idx] = (_Float16)(hn - (float)hh);
    if (writeOut) {
        if (flags[1]) ((float*)outv)[idx] = hn;
        else ((__hip_bfloat16*)outv)[idx] = __float2bfloat16(hn);
    }
}

extern "C" void kernel_launch(void* const* d_in, const int* in_sizes, int n_in,
                              void* d_out, int out_size, void* d_ws, size_t ws_size,
                              hipStream_t stream) {
    const void* hv_in   = d_in[0];
    const int* edge_src = (const int*)d_in[1];
    const int* edge_dst = (const int*)d_in[2];
    const void* msg_W = d_in[3];
    const void* msg_b = d_in[4];
    const void* gWih  = d_in[5];
    const void* gWhh  = d_in[6];
    const void* gbih  = d_in[7];
    const void* gbhh  = d_in[8];

    // ---- workspace carve-up (~112 MB, under the 127 MB proven level) ----
    char* p = (char*)d_ws;
    auto alloc = [&](size_t bytes) -> void* {
        void* r = (void*)p;
        p += (bytes + 255) & ~(size_t)255;
        return r;
    };
    int* flags   = (int*)alloc(256);
    int* deg     = (int*)alloc((size_t)NN * 4);
    int* row     = (int*)alloc((size_t)(NN + 1) * 4);
    int* counts  = (int*)alloc((size_t)NB * GG * 4);
    int* bsum    = (int*)alloc((size_t)NB * 4);
    int* bbase   = (int*)alloc((size_t)(NB + 1) * 4);
    int* offsets = (int*)alloc((size_t)NB * GG * 4);
    int* pairs   = (int*)alloc((size_t)NE * 4);        // becomes sorted csr
    _Float16* wCcH = (_Float16*)alloc((size_t)TT * 384 * 256 * 2);  // Wc hi
    _Float16* wCcL = (_Float16*)alloc((size_t)TT * 384 * 256 * 2);  // Wc lo
    _Float16* wHhH = (_Float16*)alloc((size_t)TT * 384 * 128 * 2);
    _Float16* wHhL = (_Float16*)alloc((size_t)TT * 384 * 128 * 2);
    float* bMsg = (float*)alloc((size_t)TT * 256 * 4);
    float* bIh  = (float*)alloc((size_t)TT * 384 * 4);
    float* bHh  = (float*)alloc((size_t)TT * 384 * 4);
    float* c1   = (float*)alloc((size_t)TT * 384 * 4);
    _Float16* hvH = (_Float16*)alloc((size_t)NN * HH * 2);   // 12.8 MB
    _Float16* hvL = (_Float16*)alloc((size_t)NN * HH * 2);   // 12.8 MB
    char* PA = (char*)alloc((size_t)NN * 384 * 2);           // 38.4 MB: gi
    char* PB = (char*)alloc((size_t)NN * 384 * 2);           // 38.4 MB: SH+SL -> gh
    (void)ws_size; (void)in_sizes; (void)n_in; (void)out_size;

    _Float16* gi = (_Float16*)PA;
    _Float16* SH = (_Float16*)PB;
    _Float16* SL = (_Float16*)(PB + (size_t)NN * HH * 2);
    _Float16* gh = (_Float16*)PB;   // overwrites dead S after gi-GEMM

    // ---- dtype detection + preprocessing ----
    detect_kernel<<<1, 64, 0, stream>>>((const unsigned short*)hv_in, edge_src, flags);
    split_kernel<<<(NN * HH + 255) / 256, 256, 0, stream>>>(hv_in, hvH, hvL, NN * HH, flags);
    split_kernel<<<(TT * 384 * 128 + 255) / 256, 256, 0, stream>>>(
        gWhh, wHhH, wHhL, TT * 384 * 128, flags);
    {
        int n1 = TT * 256, n2 = TT * 384, n3 = TT * 384;
        conv3_kernel<<<(n1 + n2 + n3 + 255) / 256, 256, 0, stream>>>(
            msg_b, bMsg, n1, gbih, bIh, n2, gbhh, bHh, n3, flags);
    }
    wc_kernel<<<TT * 384, 256, 0, stream>>>(gWih, msg_W, wCcH, wCcL, flags);
    c1_kernel<<<(TT * 384 + 63) / 64, 64, 0, stream>>>(gWih, bMsg, c1, flags);

    // ---- bucket-CSR build + in-bucket sort -> per-node CSR ----
    bucket_hist_kernel<<<GG, 256, 0, stream>>>(edge_dst, counts);
    bucket_sum_kernel<<<(NB + 3) / 4, 256, 0, stream>>>(counts, bsum);
    bucket_scan_kernel<<<1, 1024, 0, stream>>>(bsum, bbase);
    bucket_offsets_kernel<<<(NB + 3) / 4, 256, 0, stream>>>(counts, bbase, offsets);
    bucket_scatter_kernel<<<GG, 256, 0, stream>>>(edge_src, edge_dst, offsets, pairs, flags);
    bucket_sort_kernel<<<NB, 256, 0, stream>>>(bbase, pairs, row, deg);

    int mt128 = (NN + 127) / 128;  // 391

    for (int t = 0; t < TT; t++) {
        // S planes from per-node 8-wide gather (-> PB)
        gather_kernel<<<NN, 64, 0, stream>>>(row, pairs, hvH, SH, SL);

        // gi = f16( Wc@[deg*hv | S] + deg*c1 + bih )  -> PA
        GemmOp opi = { hvH, hvL, SH, SL, 128, 256,
                       wCcH + (size_t)t * 384 * 256, wCcL + (size_t)t * 384 * 256,
                       bIh + (size_t)t * 384, c1 + (size_t)t * 384, gi, 384, 0 };
        mfma_gemm_kernel<<<dim3(3, mt128), 256, 0, stream>>>(opi, deg, NN);

        // gh = f16( Whh@hv + bhh )  -> PB (S dead now)
        GemmOp opg = { hvH, hvL, hvH, hvL, 128, 128,
                       wHhH + (size_t)t * 384 * 128, wHhL + (size_t)t * 384 * 128,
                       bHh + (size_t)t * 384, nullptr, gh, 384, 1 };
        mfma_gemm_kernel<<<dim3(3, mt128), 256, 0, stream>>>(opg, deg, NN);

        // GRU gates; hi/lo state planes in place; dtype-aware output on last round
        gate_kernel<<<(NN * HH + 255) / 256, 256, 0, stream>>>(
            gi, gh, hvH, hvL, d_out, flags, (t == TT - 1) ? 1 : 0, NN * HH);
    }
}